// Round 10
// baseline (201.937 us; speedup 1.0000x reference)
//
#include <hip/hip_runtime.h>
#include <math.h>

#define CAP  (1u<<20)
#define LCAP 12288
#define LBUF 4096

typedef __attribute__((ext_vector_type(4))) float f32x4;
typedef __attribute__((ext_vector_type(8))) __bf16 bf16x8;
typedef __attribute__((ext_vector_type(8))) unsigned short u16x8;
typedef __attribute__((ext_vector_type(4))) unsigned short u16x4;

__device__ __forceinline__ unsigned f2key(float f){
  unsigned u = __float_as_uint(f);
  return (u & 0x80000000u) ? ~u : (u | 0x80000000u);
}
__device__ __forceinline__ float key2f(unsigned k){
  unsigned u = (k & 0x80000000u) ? (k & 0x7fffffffu) : ~k;
  return __uint_as_float(u);
}
// f32 -> bf16 bits, round-to-nearest-even
__device__ __forceinline__ unsigned short f2bf(float f){
  unsigned u = __float_as_uint(f);
  u += 0x7FFFu + ((u>>16)&1u);
  return (unsigned short)(u>>16);
}

// ---- shared matmul building blocks (MUST be bit-identical across passes) ----
__device__ __forceinline__ void stage_quant_tiles(
    const float* __restrict__ A, const float* __restrict__ B,
    unsigned short* As, unsigned short* Bs,
    const float* __restrict__ stA, const float* __restrict__ stB,
    int brow, int bcol, int tid){
  const float amn=stA[0], amx=stA[1];
  const float adiff=amx-amn, adenom=adiff+1e-8f;
  const float bmn=stB[0], bmx=stB[1];
  const float bdiff=bmx-bmn, bdenom=bdiff+1e-8f;
  const float blp=0.05f*bmx, bln=0.05f*fabsf(bmn);
  #pragma unroll
  for (int i=0;i<8;i++){
    int f = tid + i*256;
    int r = f >> 4;
    int k4 = (f & 15) << 2;
    float4 v = *(const float4*)&A[(size_t)(brow + r)*64 + k4];
    float rr[4] = {v.x,v.y,v.z,v.w};
    u16x4 qv;
    #pragma unroll
    for (int j=0;j<4;j++){
      float xv = rr[j];
      float q = fminf(fmaxf(xv, amn), amx);
      q = (q - amn) / adenom * 255.0f;
      q = rintf(q);
      q = q / 255.0f * adiff + amn;
      qv[j] = f2bf(xv + (q - xv));
    }
    unsigned slot = ((unsigned)(k4>>3)) ^ ((unsigned)r & 7u);
    *(u16x4*)&As[(unsigned)r*64u + slot*8u + (unsigned)(k4&7)] = qv;
  }
  #pragma unroll
  for (int i=0;i<4;i++){
    int u = tid + i*256;
    int col = u & 127;
    int ko = (u >> 7) << 3;
    u16x8 qv;
    #pragma unroll
    for (int j=0;j<8;j++){
      float xv = B[(size_t)(ko+j)*2048 + bcol + col];
      float q = fminf(fmaxf(xv, bmn), bmx);
      q = (q - bmn) / bdenom * 255.0f;
      q = rintf(q);
      q = q / 255.0f * bdiff + bmn;
      float pos = fmaxf(q, 0.0f);
      float neg = q - pos;
      pos = (pos < blp) ? blp : pos;
      neg = (neg > -bln) ? -bln : neg;
      q = pos + neg;
      qv[j] = f2bf(xv + (q - xv));
    }
    unsigned slot = ((unsigned)(ko>>3)) ^ ((unsigned)col & 7u);
    *(u16x8*)&Bs[(unsigned)col*64u + slot*8u] = qv;
  }
}

__device__ __forceinline__ void mfma_tile(
    const unsigned short* As, const unsigned short* Bs,
    f32x4 acc[2][8], int w, int lr, int lg){
  #pragma unroll
  for (int kk=0; kk<2; ++kk){
    bf16x8 a[2], bb[8];
    #pragma unroll
    for (int rt=0;rt<2;rt++){
      int row = w*32 + rt*16 + lr;
      unsigned slot = (unsigned)(kk*4 + lg) ^ ((unsigned)row & 7u);
      a[rt] = __builtin_bit_cast(bf16x8, *(const u16x8*)&As[(unsigned)row*64u + slot*8u]);
    }
    #pragma unroll
    for (int ct=0;ct<8;ct++){
      int col = ct*16 + lr;
      unsigned slot = (unsigned)(kk*4 + lg) ^ ((unsigned)col & 7u);
      bb[ct] = __builtin_bit_cast(bf16x8, *(const u16x8*)&Bs[(unsigned)col*64u + slot*8u]);
    }
    #pragma unroll
    for (int rt=0;rt<2;rt++)
      #pragma unroll
      for (int ct=0;ct<8;ct++)
        acc[rt][ct] = __builtin_amdgcn_mfma_f32_16x16x32_bf16(a[rt], bb[ct], acc[rt][ct], 0, 0, 0);
  }
}

// ctrl layout (unsigned words):
// [0..4096) hx | [4096..8192) hy
// 12288..12290 minkey x,y,o | 12291..12293 cnt x,y,o
// 12303 tkey | 12304.. stats (float pairs x,y,o)
// 12320..14368 blockMaxKey[2048] | 14368..16416 blockMinKey[2048]
__global__ void init_kernel(unsigned* ctrl){
  int tid = blockIdx.x*blockDim.x + threadIdx.x;
  int stride = gridDim.x*blockDim.x;
  for (int i=tid;i<8192;i+=stride) ctrl[i]=0u;
  if (tid<16) ctrl[12291+tid]=0u;
  if (tid>=16 && tid<19) ctrl[12288+(tid-16)]=0xFFFFFFFFu;
}

// 4096-bin histogram over key>>20, 8-way privatized + bank-rotated; min via shuffle.
__global__ __launch_bounds__(256) void hist2_kernel(
    const float4* __restrict__ dA, const float4* __restrict__ dB, int n4A, int n4B,
    unsigned* __restrict__ hA, unsigned* __restrict__ hB,
    unsigned* __restrict__ mkA, unsigned* __restrict__ mkB){
  const int z = blockIdx.y;
  const float4* __restrict__ data = z ? dB : dA;
  const int n4 = z ? n4B : n4A;
  unsigned* hist = z ? hB : hA;
  unsigned* minKey = z ? mkB : mkA;
  __shared__ unsigned sh[8*4096];
  int tid = threadIdx.x;
  for (int i=tid;i<8*4096;i+=blockDim.x) sh[i]=0u;
  __syncthreads();
  const unsigned p = (unsigned)(tid & 7);
  const unsigned cp = p << 12;
  const unsigned rot = p << 2;
  unsigned lmin=0xFFFFFFFFu;
  int idx = blockIdx.x*blockDim.x + tid;
  int stride = gridDim.x*blockDim.x;
  for (int i=idx;i<n4;i+=stride){
    float4 v = data[i];
    unsigned k0=f2key(v.x), k1=f2key(v.y), k2=f2key(v.z), k3=f2key(v.w);
    atomicAdd(&sh[cp + (((k0>>20)+rot)&4095u)],1u);
    atomicAdd(&sh[cp + (((k1>>20)+rot)&4095u)],1u);
    atomicAdd(&sh[cp + (((k2>>20)+rot)&4095u)],1u);
    atomicAdd(&sh[cp + (((k3>>20)+rot)&4095u)],1u);
    lmin = min(lmin, min(min(k0,k1),min(k2,k3)));
  }
  #pragma unroll
  for (int off=32; off; off>>=1) lmin = min(lmin, __shfl_xor(lmin, off));
  if ((tid&63)==0) atomicMin(minKey, lmin);
  __syncthreads();
  for (int i=tid;i<4096;i+=blockDim.x){
    unsigned c=0;
    #pragma unroll
    for (int q=0;q<8;q++) c += sh[(q<<12) + (((unsigned)i + (q<<2))&4095u)];
    if(c) atomicAdd(&hist[i],c);
  }
}

// collect elements whose bin in [b_lo, b_hi]; findbin inlined; block-staged push.
__global__ __launch_bounds__(256) void collect2_kernel(
    const float4* __restrict__ dA, const float4* __restrict__ dB, int n4A, int n4B,
    const unsigned* __restrict__ hA, const unsigned* __restrict__ hB,
    unsigned k1A, unsigned k2A, unsigned k1B, unsigned k2B,
    float* __restrict__ candA, float* __restrict__ candB,
    unsigned* __restrict__ cntA, unsigned* __restrict__ cntB){
  const int z = blockIdx.y;
  const float4* __restrict__ data = z ? dB : dA;
  const int n4 = z ? n4B : n4A;
  const unsigned* __restrict__ hist = z ? hB : hA;
  const unsigned k1 = z ? k1B : k1A;
  const unsigned k2 = z ? k2B : k2A;
  float* cand = z ? candB : candA;
  unsigned* cnt = z ? cntB : cntA;
  __shared__ float sc[LBUF];
  __shared__ unsigned part[256];
  __shared__ unsigned sBi[2];
  __shared__ unsigned scnt, sbase;
  const int t = threadIdx.x;
  if (t==0) scnt=0u;
  unsigned h[16]; unsigned s=0;
  #pragma unroll
  for (int i=0;i<16;i++){ h[i] = hist[t*16+i]; s += h[i]; }
  part[t] = s;
  __syncthreads();
  for (int off=1; off<256; off<<=1){
    unsigned add = (t+off<256) ? part[t+off] : 0u;
    __syncthreads();
    part[t] += add;
    __syncthreads();
  }
  unsigned cum = (t<255) ? part[t+1] : 0u;
  for (int i=15;i>=0;--i){
    unsigned hh = h[i];
    unsigned b = (unsigned)(t*16+i);
    if (cum < k1 && cum + hh >= k1){ sBi[1] = b; }
    if (cum < k2 && cum + hh >= k2){ sBi[0] = b; }
    cum += hh;
  }
  __syncthreads();
  const unsigned blo = sBi[0], bhi = sBi[1];
  int idx = blockIdx.x*blockDim.x + t;
  int stride = gridDim.x*blockDim.x;
  for (int i=idx;i<n4;i+=stride){
    float4 v = data[i];
    float r[4] = {v.x,v.y,v.z,v.w};
    #pragma unroll
    for (int j=0;j<4;j++){
      unsigned b = f2key(r[j]) >> 20;
      if (b>=blo && b<=bhi){
        unsigned p = atomicAdd(&scnt,1u);
        if (p < LBUF) sc[p] = r[j];
        else { unsigned g = atomicAdd(cnt,1u); if (g<CAP) cand[g]=r[j]; }
      }
    }
  }
  __syncthreads();
  unsigned c = scnt; if (c > LBUF) c = LBUF;
  if (t==0 && c>0) sbase = atomicAdd(cnt, c);
  __syncthreads();
  for (unsigned i=t; i<c; i+=256){
    unsigned g = sbase + i;
    if (g < CAP) cand[g] = sc[i];
  }
}

// exact top-k1/k2 via 4-pass radix select; 16-way bank-staggered privatized
// hist; wave-0 Kogge-Stone suffix scan. hist=nullptr -> above=0.
__global__ __launch_bounds__(1024) void select2_kernel(
    const float* __restrict__ candA, const float* __restrict__ candB,
    const unsigned* __restrict__ cntA, const unsigned* __restrict__ cntB,
    const unsigned* __restrict__ hA, const unsigned* __restrict__ hB,
    const unsigned* __restrict__ mkA, const unsigned* __restrict__ mkB,
    unsigned k1A, unsigned k2A, unsigned k1B, unsigned k2B,
    double fracA, double fracB,
    float* __restrict__ stA, float* __restrict__ stB){
  const int z = blockIdx.x;
  const float* __restrict__ cand = z ? candB : candA;
  const unsigned* cnt = z ? cntB : cntA;
  const unsigned* __restrict__ hist_g = z ? hB : hA;
  const unsigned* mk  = z ? mkB  : mkA;
  const unsigned k1 = z ? k1B : k1A;
  const unsigned k2 = z ? k2B : k2A;
  const double frac = z ? fracB : fracA;
  float* stats = z ? stB : stA;

  __shared__ unsigned keys[LCAP];
  __shared__ unsigned histP[16*258];
  __shared__ unsigned hist[256];
  __shared__ unsigned part[256];
  __shared__ unsigned sAbove;
  __shared__ unsigned sPrefix, sK;
  __shared__ unsigned sKey[2];
  const int t = threadIdx.x;
  unsigned m = *cnt; if (m > CAP) m = CAP;
  for (unsigned i=t; i<m && i<LCAP; i+=1024) keys[i] = f2key(cand[i]);

  if (t==0) sAbove = 0u;
  if (hist_g){
    unsigned h[16]; unsigned s=0;
    if (t<256){
      #pragma unroll
      for (int i=0;i<16;i++){ h[i] = hist_g[t*16+i]; s += h[i]; }
      part[t] = s;
    }
    __syncthreads();
    for (int off=1; off<256; off<<=1){
      unsigned add = (t<256 && t+off<256) ? part[t+off] : 0u;
      __syncthreads();
      if (t<256) part[t] += add;
      __syncthreads();
    }
    if (t<256){
      unsigned cum = (t<255) ? part[t+1] : 0u;
      for (int i=15;i>=0;--i){
        unsigned hh = h[i];
        if (cum < k1 && cum + hh >= k1){ sAbove = cum; }
        cum += hh;
      }
    }
  }
  __syncthreads();
  const unsigned above = sAbove;

  for (int tg=0; tg<2; ++tg){
    unsigned k = ((tg==0) ? k1 : k2) - above;
    unsigned prefix = 0u, pmask = 0u;
    for (int s=24; s>=0; s-=8){
      for (int i=t;i<16*258;i+=1024) histP[i]=0u;
      __syncthreads();
      const unsigned base = (unsigned)(t & 15) * 258u;
      for (unsigned i=t;i<m;i+=1024){
        unsigned key = (i<LCAP) ? keys[i] : f2key(cand[i]);
        if ((key & pmask) == prefix) atomicAdd(&histP[base + ((key>>s)&255u)],1u);
      }
      __syncthreads();
      if (t<256){
        unsigned c=0;
        #pragma unroll
        for (int q=0;q<16;q++) c += histP[(unsigned)q*258u + (unsigned)t];
        hist[t] = c;
      }
      __syncthreads();
      if (t<64){
        unsigned h0=hist[t*4+0], h1=hist[t*4+1], h2=hist[t*4+2], h3=hist[t*4+3];
        unsigned g = h0+h1+h2+h3;
        unsigned acc = g;
        #pragma unroll
        for (int off=1; off<64; off<<=1){
          unsigned v = __shfl_down(acc, off);
          acc += (t+off<64) ? v : 0u;
        }
        unsigned ca3 = acc - g;
        unsigned ca2 = ca3 + h3;
        unsigned ca1 = ca2 + h2;
        unsigned ca0 = ca1 + h1;
        if (ca3<k && ca3+h3>=k){ sPrefix = prefix | ((unsigned)(4*t+3)<<s); sK = k-ca3; }
        if (ca2<k && ca2+h2>=k){ sPrefix = prefix | ((unsigned)(4*t+2)<<s); sK = k-ca2; }
        if (ca1<k && ca1+h1>=k){ sPrefix = prefix | ((unsigned)(4*t+1)<<s); sK = k-ca1; }
        if (ca0<k && ca0+h0>=k){ sPrefix = prefix | ((unsigned)(4*t+0)<<s); sK = k-ca0; }
      }
      __syncthreads();
      prefix = sPrefix;
      pmask |= (255u << s);
      k = sK;
    }
    if (t==0) sKey[tg] = prefix;
    __syncthreads();
  }
  if (t==0){
    float vhi = key2f(sKey[0]);
    float vlo = key2f(sKey[1]);
    double mx = (double)vlo + frac * ((double)vhi - (double)vlo);
    float mxf = (float)mx;
    float mnraw = key2f(*mk);
    float mnf = (mnraw >= 0.0f) ? mnraw : -mxf;
    stats[0]=mnf; stats[1]=mxf;
  }
}

// PASS 1: MFMA matmul, NO C write. Per-block max/min only (shuffle-reduced).
__global__ __launch_bounds__(256) void matmul_stats_kernel(
    const float* __restrict__ A, const float* __restrict__ B,
    const float* __restrict__ stA, const float* __restrict__ stB,
    unsigned* __restrict__ bMaxKey, unsigned* __restrict__ bMinKey){
  __shared__ unsigned short As[128*64];
  __shared__ unsigned short Bs[128*64];
  __shared__ float wred[8];
  const int b = blockIdx.z;
  A += (size_t)b*2048*64;
  B += (size_t)b*64*2048;
  const int brow = blockIdx.y*128, bcol = blockIdx.x*128;
  const int tid = threadIdx.x;
  stage_quant_tiles(A, B, As, Bs, stA, stB, brow, bcol, tid);
  __syncthreads();
  const int w = tid >> 6, l = tid & 63, lr = l & 15, lg = l >> 4;
  f32x4 zero = {0.f,0.f,0.f,0.f};
  f32x4 acc[2][8];
  #pragma unroll
  for (int rt=0;rt<2;rt++)
    #pragma unroll
    for (int ct=0;ct<8;ct++) acc[rt][ct]=zero;
  mfma_tile(As, Bs, acc, w, lr, lg);
  float tmx = -3.4e38f, tmn = 3.4e38f;
  #pragma unroll
  for (int rt=0;rt<2;rt++)
    #pragma unroll
    for (int ct=0;ct<8;ct++)
      #pragma unroll
      for (int g=0; g<4; g++){
        float v = acc[rt][ct][g];
        tmx = fmaxf(tmx, v);
        tmn = fminf(tmn, v);
      }
  #pragma unroll
  for (int off=32; off; off>>=1){
    tmx = fmaxf(tmx, __shfl_xor(tmx, off));
    tmn = fminf(tmn, __shfl_xor(tmn, off));
  }
  if ((tid&63)==0){ wred[tid>>6]=tmx; wred[4+(tid>>6)]=tmn; }
  __syncthreads();
  if (tid==0){
    float m4 = fmaxf(fmaxf(wred[0],wred[1]),fmaxf(wred[2],wred[3]));
    float n4 = fminf(fminf(wred[4],wred[5]),fminf(wred[6],wred[7]));
    int bid = blockIdx.x + (blockIdx.y<<4) + (blockIdx.z<<8);
    bMaxKey[bid] = f2key(m4);
    bMinKey[bid] = f2key(n4);
  }
}

// T = kth-largest of 2048 block maxima; also global min.
__global__ __launch_bounds__(256) void thresh_kernel(
    const unsigned* __restrict__ bMaxKey, const unsigned* __restrict__ bMinKey,
    unsigned kth, unsigned* __restrict__ tkey, unsigned* __restrict__ minKeyO){
  __shared__ unsigned red[8];
  const int t = threadIdx.x;
  unsigned kz[8];
  unsigned mn = 0xFFFFFFFFu;
  #pragma unroll
  for (int i=0;i<8;i++){ kz[i] = bMaxKey[t*8+i]; mn = min(mn, bMinKey[t*8+i]); }
  #pragma unroll
  for (int off=32; off; off>>=1) mn = min(mn, __shfl_xor(mn, off));
  if ((t&63)==0) red[4+(t>>6)] = mn;
  __syncthreads();
  if (t==0) *minKeyO = min(min(red[4],red[5]),min(red[6],red[7]));
  unsigned lo=0u, hi=0xFFFFFFFFu;
  while (lo < hi){
    unsigned mid = lo + ((hi-lo)>>1) + 1u;
    unsigned c = 0;
    #pragma unroll
    for (int i=0;i<8;i++) c += (kz[i] >= mid) ? 1u : 0u;
    #pragma unroll
    for (int off=32; off; off>>=1) c += __shfl_xor(c, off);
    __syncthreads();
    if ((t&63)==0) red[t>>6] = c;
    __syncthreads();
    unsigned tot = red[0]+red[1]+red[2]+red[3];
    if (tot >= kth) lo = mid; else hi = mid - 1u;
  }
  if (t==0) *tkey = lo;
}

// Recompute C-tiles whose block-max >= T (<= kth tiles run); push values >= T.
// Bit-identical staging+MFMA to pass 1 -> exact candidate superset, no C read.
__global__ __launch_bounds__(256) void collect_tile_kernel(
    const float* __restrict__ A, const float* __restrict__ B,
    const float* __restrict__ stA, const float* __restrict__ stB,
    const unsigned* __restrict__ bMaxKey, const unsigned* __restrict__ tkey,
    float* __restrict__ cand, unsigned* __restrict__ cnt){
  const unsigned T = *tkey;
  const int bid = blockIdx.x + (blockIdx.y<<4) + (blockIdx.z<<8);
  if (bMaxKey[bid] < T) return;
  __shared__ unsigned short As[128*64];
  __shared__ unsigned short Bs[128*64];
  __shared__ float sc[LBUF];
  __shared__ unsigned scnt, sbase;
  const int b = blockIdx.z;
  A += (size_t)b*2048*64;
  B += (size_t)b*64*2048;
  const int brow = blockIdx.y*128, bcol = blockIdx.x*128;
  const int tid = threadIdx.x;
  if (tid==0) scnt=0u;
  stage_quant_tiles(A, B, As, Bs, stA, stB, brow, bcol, tid);
  __syncthreads();
  const int w = tid >> 6, l = tid & 63, lr = l & 15, lg = l >> 4;
  f32x4 zero = {0.f,0.f,0.f,0.f};
  f32x4 acc[2][8];
  #pragma unroll
  for (int rt=0;rt<2;rt++)
    #pragma unroll
    for (int ct=0;ct<8;ct++) acc[rt][ct]=zero;
  mfma_tile(As, Bs, acc, w, lr, lg);
  #pragma unroll
  for (int rt=0;rt<2;rt++)
    #pragma unroll
    for (int ct=0;ct<8;ct++)
      #pragma unroll
      for (int g=0; g<4; g++){
        float v = acc[rt][ct][g];
        if (f2key(v) >= T){
          unsigned p = atomicAdd(&scnt,1u);
          if (p < LBUF) sc[p] = v;
          else { unsigned gg = atomicAdd(cnt,1u); if (gg<CAP) cand[gg]=v; }
        }
      }
  __syncthreads();
  unsigned c = scnt; if (c > LBUF) c = LBUF;
  if (tid==0 && c>0) sbase = atomicAdd(cnt, c);
  __syncthreads();
  for (unsigned i=tid; i<c; i+=256){
    unsigned g = sbase + i;
    if (g < CAP) cand[g] = sc[i];
  }
}

// PASS 2: recompute C (bit-identical) and apply out fake-quant in the epilogue;
// writes the FINAL output once (no raw-C round trip, quant pass deleted).
__global__ __launch_bounds__(256) void matmul_quant_kernel(
    const float* __restrict__ A, const float* __restrict__ B, float* __restrict__ C,
    const float* __restrict__ stA, const float* __restrict__ stB,
    const float* __restrict__ stO){
  __shared__ unsigned short As[128*64];
  __shared__ unsigned short Bs[128*64];
  const float omn=stO[0], omx=stO[1];
  const float odiff=omx-omn, odenom=odiff+1e-8f;
  const int b = blockIdx.z;
  A += (size_t)b*2048*64;
  B += (size_t)b*64*2048;
  C += (size_t)b*2048*2048;
  const int brow = blockIdx.y*128, bcol = blockIdx.x*128;
  const int tid = threadIdx.x;
  stage_quant_tiles(A, B, As, Bs, stA, stB, brow, bcol, tid);
  __syncthreads();
  const int w = tid >> 6, l = tid & 63, lr = l & 15, lg = l >> 4;
  f32x4 zero = {0.f,0.f,0.f,0.f};
  f32x4 acc[2][8];
  #pragma unroll
  for (int rt=0;rt<2;rt++)
    #pragma unroll
    for (int ct=0;ct<8;ct++) acc[rt][ct]=zero;
  mfma_tile(As, Bs, acc, w, lr, lg);
  #pragma unroll
  for (int rt=0;rt<2;rt++)
    #pragma unroll
    for (int ct=0;ct<8;ct++)
      #pragma unroll
      for (int g=0; g<4; g++){
        float x = acc[rt][ct][g];
        float q = fminf(fmaxf(x, omn), omx);
        q = (q - omn) / odenom * 255.0f;
        q = rintf(q);
        q = q / 255.0f * odiff + omn;
        float v = x + (q - x);
        int row = brow + w*32 + rt*16 + lg*4 + g;
        int col = bcol + ct*16 + lr;
        C[(size_t)row*2048 + col] = v;
      }
}

static void percentile_ranks(long long n, double pct, unsigned& k1, unsigned& k2, double& frac){
  double p = (double)(n - 1) * (pct / 100.0);
  double fi = floor(p);
  frac = p - fi;
  long long i0 = (long long)fi;
  k2 = (unsigned)(n - i0);
  k1 = k2 - 1u;
}

extern "C" void kernel_launch(void* const* d_in, const int* in_sizes, int n_in,
                              void* d_out, int out_size, void* d_ws, size_t ws_size,
                              hipStream_t stream) {
  const float* x = (const float*)d_in[0];
  const float* y = (const float*)d_in[1];
  float* out = (float*)d_out;
  char* ws = (char*)d_ws;

  const long long nX = (long long)in_sizes[0];       // 1048576
  const long long nY = (long long)in_sizes[1];       // 1048576
  const long long nO = (long long)out_size;          // 33554432
  const int nX4 = (int)(nX/4), nY4 = (int)(nY/4);

  float*    candx = (float*)(ws);
  float*    candy = (float*)(ws + (5ll<<20));
  float*    cando = (float*)(ws + (10ll<<20));
  unsigned* ctrl  = (unsigned*)(ws + (15ll<<20));
  unsigned *hx = ctrl, *hy = ctrl+4096;
  unsigned* minkey = ctrl + 12288;   // [3]: x,y,o
  unsigned* cnt    = ctrl + 12291;   // [3]
  unsigned* tkey   = ctrl + 12303;
  float* stx = (float*)(ctrl + 12304);  // {mn,mx}
  float* sty = stx + 2;
  float* sto = stx + 4;
  unsigned* bMaxKey = ctrl + 12320;  // [2048]
  unsigned* bMinKey = ctrl + 14368;  // [2048]

  unsigned k1x,k2x,k1y,k2y,k1o,k2o; double fx,fy,fo;
  percentile_ranks(nX, 99.99,   k1x, k2x, fx);
  percentile_ranks(nY, 98.0,    k1y, k2y, fy);
  percentile_ranks(nO, 99.9999, k1o, k2o, fo);   // k1o=34, k2o=35

  init_kernel<<<32,256,0,stream>>>(ctrl);

  // ---- x & y stats (quant fused into matmul staging) ----
  hist2_kernel<<<dim3(128,2),256,0,stream>>>((const float4*)x,(const float4*)y,nX4,nY4,hx,hy,minkey+0,minkey+1);
  collect2_kernel<<<dim3(128,2),256,0,stream>>>((const float4*)x,(const float4*)y,nX4,nY4,hx,hy,
                                                k1x,k2x,k1y,k2y,candx,candy,cnt+0,cnt+1);
  select2_kernel<<<2,1024,0,stream>>>(candx,candy,cnt+0,cnt+1,hx,hy,minkey+0,minkey+1,
                                      k1x,k2x,k1y,k2y,fx,fy,stx,sty);

  // ---- pass 1: stats-only matmul (no C write) ----
  matmul_stats_kernel<<<dim3(16,16,8),256,0,stream>>>(x, y, stx, sty, bMaxKey, bMinKey);

  // ---- threshold, tile-recompute collect, select ----
  thresh_kernel<<<1,256,0,stream>>>(bMaxKey, bMinKey, k2o, tkey, minkey+2);
  collect_tile_kernel<<<dim3(16,16,8),256,0,stream>>>(x, y, stx, sty, bMaxKey, tkey, cando, cnt+2);
  select2_kernel<<<1,1024,0,stream>>>(cando,cando,cnt+2,cnt+2,(const unsigned*)nullptr,(const unsigned*)nullptr,
                                      minkey+2,minkey+2,k1o,k2o,k1o,k2o,fo,fo,sto,sto);

  // ---- pass 2: recompute + fused out-quant, single 134MB write ----
  matmul_quant_kernel<<<dim3(16,16,8),256,0,stream>>>(x, y, out, stx, sty, sto);
}

// Round 11
// 137.545 us; speedup vs baseline: 1.4681x; 1.4681x over previous
//
#include <hip/hip_runtime.h>
#include <math.h>

#define CAP  (1u<<20)
#define LCAP 12288
#define LBUF 4096

typedef __attribute__((ext_vector_type(4))) float f32x4;
typedef __attribute__((ext_vector_type(8))) __bf16 bf16x8;
typedef __attribute__((ext_vector_type(8))) unsigned short u16x8;
typedef __attribute__((ext_vector_type(4))) unsigned short u16x4;

__device__ __forceinline__ unsigned f2key(float f){
  unsigned u = __float_as_uint(f);
  return (u & 0x80000000u) ? ~u : (u | 0x80000000u);
}
__device__ __forceinline__ float key2f(unsigned k){
  unsigned u = (k & 0x80000000u) ? (k & 0x7fffffffu) : ~k;
  return __uint_as_float(u);
}
// f32 -> bf16 bits, round-to-nearest-even
__device__ __forceinline__ unsigned short f2bf(float f){
  unsigned u = __float_as_uint(f);
  u += 0x7FFFu + ((u>>16)&1u);
  return (unsigned short)(u>>16);
}

// ---- cheap bf16 staging from pre-quantized ws (pure 16B copies + XOR swizzle).
// Identical bits staged in every pass -> bit-identical MFMA across passes.
__device__ __forceinline__ void stage_bf16_tiles(
    const unsigned short* __restrict__ xq, const unsigned short* __restrict__ yqT,
    unsigned short* As, unsigned short* Bs, int brow, int bcol, int tid){
  #pragma unroll
  for (int i=0;i<4;i++){
    int u = tid + i*256;               // 1024 units: 128 rows x 8 k-octs
    int row = u >> 3, ko = (u & 7) << 3;
    u16x8 v = *(const u16x8*)&xq[(size_t)(brow+row)*64 + ko];
    unsigned slot = ((unsigned)(ko>>3)) ^ ((unsigned)row & 7u);
    *(u16x8*)&As[(unsigned)row*64u + slot*8u] = v;
  }
  #pragma unroll
  for (int i=0;i<4;i++){
    int u = tid + i*256;               // 1024 units: 128 cols x 8 k-octs
    int col = u >> 3, ko = (u & 7) << 3;
    u16x8 v = *(const u16x8*)&yqT[(size_t)(bcol+col)*64 + ko];
    unsigned slot = ((unsigned)(ko>>3)) ^ ((unsigned)col & 7u);
    *(u16x8*)&Bs[(unsigned)col*64u + slot*8u] = v;
  }
}

__device__ __forceinline__ void mfma_tile(
    const unsigned short* As, const unsigned short* Bs,
    f32x4 acc[2][8], int w, int lr, int lg){
  #pragma unroll
  for (int kk=0; kk<2; ++kk){
    bf16x8 a[2], bb[8];
    #pragma unroll
    for (int rt=0;rt<2;rt++){
      int row = w*32 + rt*16 + lr;
      unsigned slot = (unsigned)(kk*4 + lg) ^ ((unsigned)row & 7u);
      a[rt] = __builtin_bit_cast(bf16x8, *(const u16x8*)&As[(unsigned)row*64u + slot*8u]);
    }
    #pragma unroll
    for (int ct=0;ct<8;ct++){
      int col = ct*16 + lr;
      unsigned slot = (unsigned)(kk*4 + lg) ^ ((unsigned)col & 7u);
      bb[ct] = __builtin_bit_cast(bf16x8, *(const u16x8*)&Bs[(unsigned)col*64u + slot*8u]);
    }
    #pragma unroll
    for (int rt=0;rt<2;rt++)
      #pragma unroll
      for (int ct=0;ct<8;ct++)
        acc[rt][ct] = __builtin_amdgcn_mfma_f32_16x16x32_bf16(a[rt], bb[ct], acc[rt][ct], 0, 0, 0);
  }
}

// ctrl layout (unsigned words):
// [0..4096) hx | [4096..8192) hy
// 12288..12290 minkey x,y,o | 12291..12293 cnt x,y,o
// 12303 tkey | 12304.. stats (float pairs x,y,o)
// 12320..14368 blockMaxKey[2048] | 14368..16416 blockMinKey[2048]
__global__ void init_kernel(unsigned* ctrl){
  int tid = blockIdx.x*blockDim.x + threadIdx.x;
  int stride = gridDim.x*blockDim.x;
  for (int i=tid;i<8192;i+=stride) ctrl[i]=0u;
  if (tid<16) ctrl[12291+tid]=0u;
  if (tid>=16 && tid<19) ctrl[12288+(tid-16)]=0xFFFFFFFFu;
}

// 4096-bin histogram over key>>20, 8-way privatized + bank-rotated; min via shuffle.
__global__ __launch_bounds__(256) void hist2_kernel(
    const float4* __restrict__ dA, const float4* __restrict__ dB, int n4A, int n4B,
    unsigned* __restrict__ hA, unsigned* __restrict__ hB,
    unsigned* __restrict__ mkA, unsigned* __restrict__ mkB){
  const int z = blockIdx.y;
  const float4* __restrict__ data = z ? dB : dA;
  const int n4 = z ? n4B : n4A;
  unsigned* hist = z ? hB : hA;
  unsigned* minKey = z ? mkB : mkA;
  __shared__ unsigned sh[8*4096];
  int tid = threadIdx.x;
  for (int i=tid;i<8*4096;i+=blockDim.x) sh[i]=0u;
  __syncthreads();
  const unsigned p = (unsigned)(tid & 7);
  const unsigned cp = p << 12;
  const unsigned rot = p << 2;
  unsigned lmin=0xFFFFFFFFu;
  int idx = blockIdx.x*blockDim.x + tid;
  int stride = gridDim.x*blockDim.x;
  for (int i=idx;i<n4;i+=stride){
    float4 v = data[i];
    unsigned k0=f2key(v.x), k1=f2key(v.y), k2=f2key(v.z), k3=f2key(v.w);
    atomicAdd(&sh[cp + (((k0>>20)+rot)&4095u)],1u);
    atomicAdd(&sh[cp + (((k1>>20)+rot)&4095u)],1u);
    atomicAdd(&sh[cp + (((k2>>20)+rot)&4095u)],1u);
    atomicAdd(&sh[cp + (((k3>>20)+rot)&4095u)],1u);
    lmin = min(lmin, min(min(k0,k1),min(k2,k3)));
  }
  #pragma unroll
  for (int off=32; off; off>>=1) lmin = min(lmin, __shfl_xor(lmin, off));
  if ((tid&63)==0) atomicMin(minKey, lmin);
  __syncthreads();
  for (int i=tid;i<4096;i+=blockDim.x){
    unsigned c=0;
    #pragma unroll
    for (int q=0;q<8;q++) c += sh[(q<<12) + (((unsigned)i + (q<<2))&4095u)];
    if(c) atomicAdd(&hist[i],c);
  }
}

// collect elements whose bin in [b_lo, b_hi]; findbin inlined; block-staged push.
__global__ __launch_bounds__(256) void collect2_kernel(
    const float4* __restrict__ dA, const float4* __restrict__ dB, int n4A, int n4B,
    const unsigned* __restrict__ hA, const unsigned* __restrict__ hB,
    unsigned k1A, unsigned k2A, unsigned k1B, unsigned k2B,
    float* __restrict__ candA, float* __restrict__ candB,
    unsigned* __restrict__ cntA, unsigned* __restrict__ cntB){
  const int z = blockIdx.y;
  const float4* __restrict__ data = z ? dB : dA;
  const int n4 = z ? n4B : n4A;
  const unsigned* __restrict__ hist = z ? hB : hA;
  const unsigned k1 = z ? k1B : k1A;
  const unsigned k2 = z ? k2B : k2A;
  float* cand = z ? candB : candA;
  unsigned* cnt = z ? cntB : cntA;
  __shared__ float sc[LBUF];
  __shared__ unsigned part[256];
  __shared__ unsigned sBi[2];
  __shared__ unsigned scnt, sbase;
  const int t = threadIdx.x;
  if (t==0) scnt=0u;
  unsigned h[16]; unsigned s=0;
  #pragma unroll
  for (int i=0;i<16;i++){ h[i] = hist[t*16+i]; s += h[i]; }
  part[t] = s;
  __syncthreads();
  for (int off=1; off<256; off<<=1){
    unsigned add = (t+off<256) ? part[t+off] : 0u;
    __syncthreads();
    part[t] += add;
    __syncthreads();
  }
  unsigned cum = (t<255) ? part[t+1] : 0u;
  for (int i=15;i>=0;--i){
    unsigned hh = h[i];
    unsigned b = (unsigned)(t*16+i);
    if (cum < k1 && cum + hh >= k1){ sBi[1] = b; }
    if (cum < k2 && cum + hh >= k2){ sBi[0] = b; }
    cum += hh;
  }
  __syncthreads();
  const unsigned blo = sBi[0], bhi = sBi[1];
  int idx = blockIdx.x*blockDim.x + t;
  int stride = gridDim.x*blockDim.x;
  for (int i=idx;i<n4;i+=stride){
    float4 v = data[i];
    float r[4] = {v.x,v.y,v.z,v.w};
    #pragma unroll
    for (int j=0;j<4;j++){
      unsigned b = f2key(r[j]) >> 20;
      if (b>=blo && b<=bhi){
        unsigned p = atomicAdd(&scnt,1u);
        if (p < LBUF) sc[p] = r[j];
        else { unsigned g = atomicAdd(cnt,1u); if (g<CAP) cand[g]=r[j]; }
      }
    }
  }
  __syncthreads();
  unsigned c = scnt; if (c > LBUF) c = LBUF;
  if (t==0 && c>0) sbase = atomicAdd(cnt, c);
  __syncthreads();
  for (unsigned i=t; i<c; i+=256){
    unsigned g = sbase + i;
    if (g < CAP) cand[g] = sc[i];
  }
}

// exact top-k1/k2 via 4-pass radix select; 16-way bank-staggered privatized
// hist; wave-0 Kogge-Stone suffix scan. hist=nullptr -> above=0.
__global__ __launch_bounds__(1024) void select2_kernel(
    const float* __restrict__ candA, const float* __restrict__ candB,
    const unsigned* __restrict__ cntA, const unsigned* __restrict__ cntB,
    const unsigned* __restrict__ hA, const unsigned* __restrict__ hB,
    const unsigned* __restrict__ mkA, const unsigned* __restrict__ mkB,
    unsigned k1A, unsigned k2A, unsigned k1B, unsigned k2B,
    double fracA, double fracB,
    float* __restrict__ stA, float* __restrict__ stB){
  const int z = blockIdx.x;
  const float* __restrict__ cand = z ? candB : candA;
  const unsigned* cnt = z ? cntB : cntA;
  const unsigned* __restrict__ hist_g = z ? hB : hA;
  const unsigned* mk  = z ? mkB  : mkA;
  const unsigned k1 = z ? k1B : k1A;
  const unsigned k2 = z ? k2B : k2A;
  const double frac = z ? fracB : fracA;
  float* stats = z ? stB : stA;

  __shared__ unsigned keys[LCAP];
  __shared__ unsigned histP[16*258];
  __shared__ unsigned hist[256];
  __shared__ unsigned part[256];
  __shared__ unsigned sAbove;
  __shared__ unsigned sPrefix, sK;
  __shared__ unsigned sKey[2];
  const int t = threadIdx.x;
  unsigned m = *cnt; if (m > CAP) m = CAP;
  for (unsigned i=t; i<m && i<LCAP; i+=1024) keys[i] = f2key(cand[i]);

  if (t==0) sAbove = 0u;
  if (hist_g){
    unsigned h[16]; unsigned s=0;
    if (t<256){
      #pragma unroll
      for (int i=0;i<16;i++){ h[i] = hist_g[t*16+i]; s += h[i]; }
      part[t] = s;
    }
    __syncthreads();
    for (int off=1; off<256; off<<=1){
      unsigned add = (t<256 && t+off<256) ? part[t+off] : 0u;
      __syncthreads();
      if (t<256) part[t] += add;
      __syncthreads();
    }
    if (t<256){
      unsigned cum = (t<255) ? part[t+1] : 0u;
      for (int i=15;i>=0;--i){
        unsigned hh = h[i];
        if (cum < k1 && cum + hh >= k1){ sAbove = cum; }
        cum += hh;
      }
    }
  }
  __syncthreads();
  const unsigned above = sAbove;

  for (int tg=0; tg<2; ++tg){
    unsigned k = ((tg==0) ? k1 : k2) - above;
    unsigned prefix = 0u, pmask = 0u;
    for (int s=24; s>=0; s-=8){
      for (int i=t;i<16*258;i+=1024) histP[i]=0u;
      __syncthreads();
      const unsigned base = (unsigned)(t & 15) * 258u;
      for (unsigned i=t;i<m;i+=1024){
        unsigned key = (i<LCAP) ? keys[i] : f2key(cand[i]);
        if ((key & pmask) == prefix) atomicAdd(&histP[base + ((key>>s)&255u)],1u);
      }
      __syncthreads();
      if (t<256){
        unsigned c=0;
        #pragma unroll
        for (int q=0;q<16;q++) c += histP[(unsigned)q*258u + (unsigned)t];
        hist[t] = c;
      }
      __syncthreads();
      if (t<64){
        unsigned h0=hist[t*4+0], h1=hist[t*4+1], h2=hist[t*4+2], h3=hist[t*4+3];
        unsigned g = h0+h1+h2+h3;
        unsigned acc = g;
        #pragma unroll
        for (int off=1; off<64; off<<=1){
          unsigned v = __shfl_down(acc, off);
          acc += (t+off<64) ? v : 0u;
        }
        unsigned ca3 = acc - g;
        unsigned ca2 = ca3 + h3;
        unsigned ca1 = ca2 + h2;
        unsigned ca0 = ca1 + h1;
        if (ca3<k && ca3+h3>=k){ sPrefix = prefix | ((unsigned)(4*t+3)<<s); sK = k-ca3; }
        if (ca2<k && ca2+h2>=k){ sPrefix = prefix | ((unsigned)(4*t+2)<<s); sK = k-ca2; }
        if (ca1<k && ca1+h1>=k){ sPrefix = prefix | ((unsigned)(4*t+1)<<s); sK = k-ca1; }
        if (ca0<k && ca0+h0>=k){ sPrefix = prefix | ((unsigned)(4*t+0)<<s); sK = k-ca0; }
      }
      __syncthreads();
      prefix = sPrefix;
      pmask |= (255u << s);
      k = sK;
    }
    if (t==0) sKey[tg] = prefix;
    __syncthreads();
  }
  if (t==0){
    float vhi = key2f(sKey[0]);
    float vlo = key2f(sKey[1]);
    double mx = (double)vlo + frac * ((double)vhi - (double)vlo);
    float mxf = (float)mx;
    float mnraw = key2f(*mk);
    float mnf = (mnraw >= 0.0f) ? mnraw : -mxf;
    stats[0]=mnf; stats[1]=mxf;
  }
}

// One-time quantization to ws: xq = bf16(fakequant(x)) row-major [b*2048+row][k];
// yqT = bf16(fakequant_lut(y)) TRANSPOSED [b*2048+col][k] (LDS 64x64 tile transpose).
__global__ __launch_bounds__(256) void prep_quant_kernel(
    const float4* __restrict__ x, const float* __restrict__ y,
    unsigned short* __restrict__ xq, unsigned short* __restrict__ yqT,
    int n4x, const float* __restrict__ stA, const float* __restrict__ stB){
  if (blockIdx.y == 0){
    const float amn=stA[0], amx=stA[1];
    const float adiff=amx-amn, adenom=adiff+1e-8f;
    int idx = blockIdx.x*256 + threadIdx.x;
    int stride = gridDim.x*256;
    for (int i=idx; i<n4x; i+=stride){
      float4 v = x[i];
      float rr[4]={v.x,v.y,v.z,v.w};
      u16x4 qv;
      #pragma unroll
      for (int j=0;j<4;j++){
        float xv = rr[j];
        float q = fminf(fmaxf(xv, amn), amx);
        q = (q - amn) / adenom * 255.0f;
        q = rintf(q);
        q = q / 255.0f * adiff + amn;
        qv[j] = f2bf(xv + (q - xv));
      }
      *(u16x4*)&xq[(size_t)i*4] = qv;
    }
  } else {
    __shared__ unsigned short Ys[64*72];
    const float bmn=stB[0], bmx=stB[1];
    const float bdiff=bmx-bmn, bdenom=bdiff+1e-8f;
    const float blp=0.05f*bmx, bln=0.05f*fabsf(bmn);
    const int blk = blockIdx.x;          // 256 blocks: 8 batches x 32 col-tiles
    const int b = blk >> 5, ctile = blk & 31;
    const float* Y = y + (size_t)b*64*2048 + ctile*64;
    const int t = threadIdx.x;
    #pragma unroll
    for (int i=0;i<4;i++){
      int u = t + i*256;                 // 1024 float4: 64 k-rows x 16 float4
      int k = u >> 4;
      int c4 = (u & 15) << 2;
      float4 v = *(const float4*)&Y[(size_t)k*2048 + c4];
      float rr[4]={v.x,v.y,v.z,v.w};
      #pragma unroll
      for (int j=0;j<4;j++){
        float xv = rr[j];
        float q = fminf(fmaxf(xv, bmn), bmx);
        q = (q - bmn) / bdenom * 255.0f;
        q = rintf(q);
        q = q / 255.0f * bdiff + bmn;
        float pos = fmaxf(q, 0.0f);
        float neg = q - pos;
        pos = (pos < blp) ? blp : pos;
        neg = (neg > -bln) ? -bln : neg;
        q = pos + neg;
        Ys[(c4+j)*72 + k] = f2bf(xv + (q - xv));
      }
    }
    __syncthreads();
    #pragma unroll
    for (int i=0;i<2;i++){
      int u = t + i*256;                 // 512 units: 64 cols x 8 k-octs
      int col = u >> 3, ko = (u & 7) << 3;
      u16x8 v = *(const u16x8*)&Ys[col*72 + ko];
      *(u16x8*)&yqT[((size_t)b*2048 + ctile*64 + col)*64 + ko] = v;
    }
  }
}

// PASS 1: MFMA matmul from ws bf16, NO C write; per-block max/min via shuffles.
__global__ __launch_bounds__(256) void matmul_stats_kernel(
    const unsigned short* __restrict__ xq, const unsigned short* __restrict__ yqT,
    unsigned* __restrict__ bMaxKey, unsigned* __restrict__ bMinKey){
  __shared__ unsigned short As[128*64];
  __shared__ unsigned short Bs[128*64];
  __shared__ float wred[8];
  const int b = blockIdx.z;
  xq  += (size_t)b*2048*64;
  yqT += (size_t)b*2048*64;
  const int brow = blockIdx.y*128, bcol = blockIdx.x*128;
  const int tid = threadIdx.x;
  stage_bf16_tiles(xq, yqT, As, Bs, brow, bcol, tid);
  __syncthreads();
  const int w = tid >> 6, l = tid & 63, lr = l & 15, lg = l >> 4;
  f32x4 zero = {0.f,0.f,0.f,0.f};
  f32x4 acc[2][8];
  #pragma unroll
  for (int rt=0;rt<2;rt++)
    #pragma unroll
    for (int ct=0;ct<8;ct++) acc[rt][ct]=zero;
  mfma_tile(As, Bs, acc, w, lr, lg);
  float tmx = -3.4e38f, tmn = 3.4e38f;
  #pragma unroll
  for (int rt=0;rt<2;rt++)
    #pragma unroll
    for (int ct=0;ct<8;ct++)
      #pragma unroll
      for (int g=0; g<4; g++){
        float v = acc[rt][ct][g];
        tmx = fmaxf(tmx, v);
        tmn = fminf(tmn, v);
      }
  #pragma unroll
  for (int off=32; off; off>>=1){
    tmx = fmaxf(tmx, __shfl_xor(tmx, off));
    tmn = fminf(tmn, __shfl_xor(tmn, off));
  }
  if ((tid&63)==0){ wred[tid>>6]=tmx; wred[4+(tid>>6)]=tmn; }
  __syncthreads();
  if (tid==0){
    float m4 = fmaxf(fmaxf(wred[0],wred[1]),fmaxf(wred[2],wred[3]));
    float n4 = fminf(fminf(wred[4],wred[5]),fminf(wred[6],wred[7]));
    int bid = blockIdx.x + (blockIdx.y<<4) + (blockIdx.z<<8);
    bMaxKey[bid] = f2key(m4);
    bMinKey[bid] = f2key(n4);
  }
}

// T = kth-largest of 2048 block maxima; also global min.
__global__ __launch_bounds__(256) void thresh_kernel(
    const unsigned* __restrict__ bMaxKey, const unsigned* __restrict__ bMinKey,
    unsigned kth, unsigned* __restrict__ tkey, unsigned* __restrict__ minKeyO){
  __shared__ unsigned red[8];
  const int t = threadIdx.x;
  unsigned kz[8];
  unsigned mn = 0xFFFFFFFFu;
  #pragma unroll
  for (int i=0;i<8;i++){ kz[i] = bMaxKey[t*8+i]; mn = min(mn, bMinKey[t*8+i]); }
  #pragma unroll
  for (int off=32; off; off>>=1) mn = min(mn, __shfl_xor(mn, off));
  if ((t&63)==0) red[4+(t>>6)] = mn;
  __syncthreads();
  if (t==0) *minKeyO = min(min(red[4],red[5]),min(red[6],red[7]));
  unsigned lo=0u, hi=0xFFFFFFFFu;
  while (lo < hi){
    unsigned mid = lo + ((hi-lo)>>1) + 1u;
    unsigned c = 0;
    #pragma unroll
    for (int i=0;i<8;i++) c += (kz[i] >= mid) ? 1u : 0u;
    #pragma unroll
    for (int off=32; off; off>>=1) c += __shfl_xor(c, off);
    __syncthreads();
    if ((t&63)==0) red[t>>6] = c;
    __syncthreads();
    unsigned tot = red[0]+red[1]+red[2]+red[3];
    if (tot >= kth) lo = mid; else hi = mid - 1u;
  }
  if (t==0) *tkey = lo;
}

// Recompute C-tiles whose block-max >= T (<= kth tiles run); push values >= T.
__global__ __launch_bounds__(256) void collect_tile_kernel(
    const unsigned short* __restrict__ xq, const unsigned short* __restrict__ yqT,
    const unsigned* __restrict__ bMaxKey, const unsigned* __restrict__ tkey,
    float* __restrict__ cand, unsigned* __restrict__ cnt){
  const unsigned T = *tkey;
  const int bid = blockIdx.x + (blockIdx.y<<4) + (blockIdx.z<<8);
  if (bMaxKey[bid] < T) return;
  __shared__ unsigned short As[128*64];
  __shared__ unsigned short Bs[128*64];
  __shared__ float sc[LBUF];
  __shared__ unsigned scnt, sbase;
  const int b = blockIdx.z;
  xq  += (size_t)b*2048*64;
  yqT += (size_t)b*2048*64;
  const int brow = blockIdx.y*128, bcol = blockIdx.x*128;
  const int tid = threadIdx.x;
  if (tid==0) scnt=0u;
  stage_bf16_tiles(xq, yqT, As, Bs, brow, bcol, tid);
  __syncthreads();
  const int w = tid >> 6, l = tid & 63, lr = l & 15, lg = l >> 4;
  f32x4 zero = {0.f,0.f,0.f,0.f};
  f32x4 acc[2][8];
  #pragma unroll
  for (int rt=0;rt<2;rt++)
    #pragma unroll
    for (int ct=0;ct<8;ct++) acc[rt][ct]=zero;
  mfma_tile(As, Bs, acc, w, lr, lg);
  #pragma unroll
  for (int rt=0;rt<2;rt++)
    #pragma unroll
    for (int ct=0;ct<8;ct++)
      #pragma unroll
      for (int g=0; g<4; g++){
        float v = acc[rt][ct][g];
        if (f2key(v) >= T){
          unsigned p = atomicAdd(&scnt,1u);
          if (p < LBUF) sc[p] = v;
          else { unsigned gg = atomicAdd(cnt,1u); if (gg<CAP) cand[gg]=v; }
        }
      }
  __syncthreads();
  unsigned c = scnt; if (c > LBUF) c = LBUF;
  if (tid==0 && c>0) sbase = atomicAdd(cnt, c);
  __syncthreads();
  for (unsigned i=tid; i<c; i+=256){
    unsigned g = sbase + i;
    if (g < CAP) cand[g] = sc[i];
  }
}

// PASS 2: recompute C (bit-identical) + fused out fake-quant; single 134MB write.
__global__ __launch_bounds__(256) void matmul_quant_kernel(
    const unsigned short* __restrict__ xq, const unsigned short* __restrict__ yqT,
    float* __restrict__ C, const float* __restrict__ stO){
  __shared__ unsigned short As[128*64];
  __shared__ unsigned short Bs[128*64];
  const float omn=stO[0], omx=stO[1];
  const float odiff=omx-omn, odenom=odiff+1e-8f;
  const int b = blockIdx.z;
  xq  += (size_t)b*2048*64;
  yqT += (size_t)b*2048*64;
  C   += (size_t)b*2048*2048;
  const int brow = blockIdx.y*128, bcol = blockIdx.x*128;
  const int tid = threadIdx.x;
  stage_bf16_tiles(xq, yqT, As, Bs, brow, bcol, tid);
  __syncthreads();
  const int w = tid >> 6, l = tid & 63, lr = l & 15, lg = l >> 4;
  f32x4 zero = {0.f,0.f,0.f,0.f};
  f32x4 acc[2][8];
  #pragma unroll
  for (int rt=0;rt<2;rt++)
    #pragma unroll
    for (int ct=0;ct<8;ct++) acc[rt][ct]=zero;
  mfma_tile(As, Bs, acc, w, lr, lg);
  #pragma unroll
  for (int rt=0;rt<2;rt++)
    #pragma unroll
    for (int ct=0;ct<8;ct++)
      #pragma unroll
      for (int g=0; g<4; g++){
        float x = acc[rt][ct][g];
        float q = fminf(fmaxf(x, omn), omx);
        q = (q - omn) / odenom * 255.0f;
        q = rintf(q);
        q = q / 255.0f * odiff + omn;
        float v = x + (q - x);
        int row = brow + w*32 + rt*16 + lg*4 + g;
        int col = bcol + ct*16 + lr;
        C[(size_t)row*2048 + col] = v;
      }
}

static void percentile_ranks(long long n, double pct, unsigned& k1, unsigned& k2, double& frac){
  double p = (double)(n - 1) * (pct / 100.0);
  double fi = floor(p);
  frac = p - fi;
  long long i0 = (long long)fi;
  k2 = (unsigned)(n - i0);
  k1 = k2 - 1u;
}

extern "C" void kernel_launch(void* const* d_in, const int* in_sizes, int n_in,
                              void* d_out, int out_size, void* d_ws, size_t ws_size,
                              hipStream_t stream) {
  const float* x = (const float*)d_in[0];
  const float* y = (const float*)d_in[1];
  float* out = (float*)d_out;
  char* ws = (char*)d_ws;

  const long long nX = (long long)in_sizes[0];       // 1048576
  const long long nY = (long long)in_sizes[1];       // 1048576
  const long long nO = (long long)out_size;          // 33554432
  const int nX4 = (int)(nX/4), nY4 = (int)(nY/4);

  float*    candx = (float*)(ws);                    // 4MB cap
  float*    candy = (float*)(ws + (5ll<<20));
  float*    cando = (float*)(ws + (10ll<<20));
  unsigned* ctrl  = (unsigned*)(ws + (15ll<<20));
  unsigned short* xq  = (unsigned short*)(ws + (16ll<<20));  // 2MB bf16
  unsigned short* yqT = (unsigned short*)(ws + (18ll<<20));  // 2MB bf16 (transposed)
  unsigned *hx = ctrl, *hy = ctrl+4096;
  unsigned* minkey = ctrl + 12288;   // [3]: x,y,o
  unsigned* cnt    = ctrl + 12291;   // [3]
  unsigned* tkey   = ctrl + 12303;
  float* stx = (float*)(ctrl + 12304);  // {mn,mx}
  float* sty = stx + 2;
  float* sto = stx + 4;
  unsigned* bMaxKey = ctrl + 12320;  // [2048]
  unsigned* bMinKey = ctrl + 14368;  // [2048]

  unsigned k1x,k2x,k1y,k2y,k1o,k2o; double fx,fy,fo;
  percentile_ranks(nX, 99.99,   k1x, k2x, fx);
  percentile_ranks(nY, 98.0,    k1y, k2y, fy);
  percentile_ranks(nO, 99.9999, k1o, k2o, fo);   // k1o=34, k2o=35

  init_kernel<<<32,256,0,stream>>>(ctrl);

  // ---- x & y stats on raw tensors ----
  hist2_kernel<<<dim3(128,2),256,0,stream>>>((const float4*)x,(const float4*)y,nX4,nY4,hx,hy,minkey+0,minkey+1);
  collect2_kernel<<<dim3(128,2),256,0,stream>>>((const float4*)x,(const float4*)y,nX4,nY4,hx,hy,
                                                k1x,k2x,k1y,k2y,candx,candy,cnt+0,cnt+1);
  select2_kernel<<<2,1024,0,stream>>>(candx,candy,cnt+0,cnt+1,hx,hy,minkey+0,minkey+1,
                                      k1x,k2x,k1y,k2y,fx,fy,stx,sty);

  // ---- one-time quantize to bf16 ws (x row-major, y transposed) ----
  prep_quant_kernel<<<dim3(256,2),256,0,stream>>>((const float4*)x, y, xq, yqT, nX4, stx, sty);

  // ---- pass 1: stats-only matmul (no C write) ----
  matmul_stats_kernel<<<dim3(16,16,8),256,0,stream>>>(xq, yqT, bMaxKey, bMinKey);

  // ---- threshold, tile-recompute collect, select ----
  thresh_kernel<<<1,256,0,stream>>>(bMaxKey, bMinKey, k2o, tkey, minkey+2);
  collect_tile_kernel<<<dim3(16,16,8),256,0,stream>>>(xq, yqT, bMaxKey, tkey, cando, cnt+2);
  select2_kernel<<<1,1024,0,stream>>>(cando,cando,cnt+2,cnt+2,(const unsigned*)nullptr,(const unsigned*)nullptr,
                                      minkey+2,minkey+2,k1o,k2o,k1o,k2o,fo,fo,sto,sto);

  // ---- pass 2: recompute + fused out-quant, single 134MB write ----
  matmul_quant_kernel<<<dim3(16,16,8),256,0,stream>>>(xq, yqT, out, sto);
}